// Round 10
// baseline (269.126 us; speedup 1.0000x reference)
//
#include <hip/hip_runtime.h>
#include <math.h>

#define Bb   4
#define Nn   2048
#define Dd   256
#define Hh   4
#define HDd  64
#define BN   (Bb * Nn)

typedef float v4f __attribute__((ext_vector_type(4)));
typedef short v8s __attribute__((ext_vector_type(8)));

__device__ __forceinline__ unsigned rne_bf16(float f) {
    unsigned u = __float_as_uint(f);
    u += 0x7fffu + ((u >> 16) & 1u);
    return u >> 16;
}

// ---------------------------------------------------------------------------
// v11: ONE fused kernel.  512 blocks x 512 threads, all co-resident
// (2 blocks/CU: LDS 68KB <= 80KB, VGPR capped 128 by launch_bounds(512,4)).
// Phase 1: bid<256  -> gemm pair (two mtiles, one head; W-tile shared in LDS)
//          bid>=256 -> adj->bitmask compress, ONE b per block group.
// Producer signals: gflag[b][h] (16 gemm blocks) / cflag[b] (64 compress
// blocks) via __threadfence + device-scope atomicAdd.
// Phase 2: v10's aggr tile (unchanged logic), gated by a tid-0 spin on its
// (b,h) flags + acquire fence -> aggr overlaps the remaining phase-1 work
// instead of waiting for a kernel boundary.
// Deadlock-free: phase-1 has no cross-block deps and all blocks are
// resident, so flags always reach their targets.
// ---------------------------------------------------------------------------
__global__ __launch_bounds__(512, 4) void k_fused(const float* __restrict__ x,
                                                  const float* __restrict__ W,
                                                  const float* __restrict__ a_src,
                                                  const float* __restrict__ a_dst,
                                                  const float* __restrict__ adj,
                                                  unsigned short* __restrict__ hbf,
                                                  float* __restrict__ ssrc,
                                                  float* __restrict__ sdst,
                                                  unsigned long long* __restrict__ bitadj,
                                                  unsigned* __restrict__ flags,
                                                  float* __restrict__ out) {
    __shared__ __align__(16) union {
        struct {                                   // phase 1 (gemm): 55.8 KB
            unsigned short xs[2][2][4608];         // [mtile-half][hi/lo][64*72]
            unsigned short wsm[2][4608];           // shared W tile (hi/lo)
            float asd[128];
        } p1;
        struct {                                   // phase 2 (aggr): 68 KB
            unsigned short Btile[2][4][2048];
            float dtab[4096];
            float red[4][64][20];
        } p2;
    } sm;

    const int tid = threadIdx.x;
    const int bid = (int)blockIdx.x;

    // =====================  PHASE 1  =====================
    if (bid < 256) {
        // ---- gemm: two mtiles (2*mt2, 2*mt2+1), one head ----
        const int head = bid & 3;
        const int mt2  = bid >> 2;                 // 0..63
        const int half = tid >> 8;                 // which mtile
        const int tl   = tid & 255;
        const int mtile = mt2 * 2 + half;
        const int m0 = mtile * 64;
        const int n0 = head * 64;
        const int b = m0 >> 11;
        const int i0loc = m0 & 2047;

        if (tid < 128) {
            int sel = tid >> 6, d = tid & 63;
            sm.p1.asd[tid] = sel ? a_dst[n0 + d] : a_src[n0 + d];
        }

        unsigned short* xsh = sm.p1.xs[half][0];
        unsigned short* xsl = sm.p1.xs[half][1];
        unsigned short* wh0 = sm.p1.wsm[0];
        unsigned short* wl0 = sm.p1.wsm[1];

        const int wv = tl >> 6, ln = tl & 63, l15 = ln & 15, l4 = ln >> 4;
        const int mh = wv >> 1, nh = wv & 1;
        const int srow = tl >> 2, kq = (tl & 3) * 16;

        v4f acc[2][2];
#pragma unroll
        for (int gg = 0; gg < 2; ++gg)
#pragma unroll
            for (int t = 0; t < 2; ++t) acc[gg][t] = (v4f){0.f, 0.f, 0.f, 0.f};

        for (int st = 0; st < 4; ++st) {
            const int k0 = st * 64;
            __syncthreads();
            {   // stage x (both halves) + W (half 0 only; shared tile)
                float xf[16];
                const float* xp = x + (size_t)(m0 + srow) * Dd + k0 + kq;
#pragma unroll
                for (int q = 0; q < 4; ++q)
                    *(float4*)&xf[q * 4] = *(const float4*)(xp + q * 4);
                unsigned xh[8], xl8[8];
#pragma unroll
                for (int j = 0; j < 8; ++j) {
                    unsigned h0 = rne_bf16(xf[2 * j]), h1 = rne_bf16(xf[2 * j + 1]);
                    float l0 = xf[2 * j] - __uint_as_float(h0 << 16);
                    float l1 = xf[2 * j + 1] - __uint_as_float(h1 << 16);
                    xh[j] = h0 | (h1 << 16);
                    xl8[j] = rne_bf16(l0) | (rne_bf16(l1) << 16);
                }
                *(uint4*)(xsh + srow * 72 + kq)     = make_uint4(xh[0], xh[1], xh[2], xh[3]);
                *(uint4*)(xsh + srow * 72 + kq + 8) = make_uint4(xh[4], xh[5], xh[6], xh[7]);
                *(uint4*)(xsl + srow * 72 + kq)     = make_uint4(xl8[0], xl8[1], xl8[2], xl8[3]);
                *(uint4*)(xsl + srow * 72 + kq + 8) = make_uint4(xl8[4], xl8[5], xl8[6], xl8[7]);
                if (half == 0) {
                    float wf[16];
                    const float* wp = W + (size_t)(n0 + srow) * Dd + k0 + kq;
#pragma unroll
                    for (int q = 0; q < 4; ++q)
                        *(float4*)&wf[q * 4] = *(const float4*)(wp + q * 4);
                    unsigned wh[8], wl[8];
#pragma unroll
                    for (int j = 0; j < 8; ++j) {
                        unsigned g0 = rne_bf16(wf[2 * j]), g1 = rne_bf16(wf[2 * j + 1]);
                        float m0f = wf[2 * j] - __uint_as_float(g0 << 16);
                        float m1f = wf[2 * j + 1] - __uint_as_float(g1 << 16);
                        wh[j] = g0 | (g1 << 16);
                        wl[j] = rne_bf16(m0f) | (rne_bf16(m1f) << 16);
                    }
                    *(uint4*)(wh0 + srow * 72 + kq)     = make_uint4(wh[0], wh[1], wh[2], wh[3]);
                    *(uint4*)(wh0 + srow * 72 + kq + 8) = make_uint4(wh[4], wh[5], wh[6], wh[7]);
                    *(uint4*)(wl0 + srow * 72 + kq)     = make_uint4(wl[0], wl[1], wl[2], wl[3]);
                    *(uint4*)(wl0 + srow * 72 + kq + 8) = make_uint4(wl[4], wl[5], wl[6], wl[7]);
                }
            }
            __syncthreads();
            {   // MFMA: wave (mh, nh) of this half owns 2x2 16-tiles
                v8s ah[2][2], al[2][2], bh_[2][2], bl_[2][2];
#pragma unroll
                for (int gg = 0; gg < 2; ++gg)
#pragma unroll
                    for (int kh = 0; kh < 2; ++kh) {
                        int ro = (mh * 32 + gg * 16 + l15) * 72 + kh * 32 + l4 * 8;
                        ah[gg][kh] = *(const v8s*)(xsh + ro);
                        al[gg][kh] = *(const v8s*)(xsl + ro);
                    }
#pragma unroll
                for (int t = 0; t < 2; ++t)
#pragma unroll
                    for (int kh = 0; kh < 2; ++kh) {
                        int ro = (nh * 32 + t * 16 + l15) * 72 + kh * 32 + l4 * 8;
                        bh_[t][kh] = *(const v8s*)(wh0 + ro);
                        bl_[t][kh] = *(const v8s*)(wl0 + ro);
                    }
#pragma unroll
                for (int gg = 0; gg < 2; ++gg)
#pragma unroll
                    for (int t = 0; t < 2; ++t)
#pragma unroll
                        for (int kh = 0; kh < 2; ++kh) {
                            acc[gg][t] = __builtin_amdgcn_mfma_f32_16x16x32_bf16(ah[gg][kh], bh_[t][kh], acc[gg][t], 0, 0, 0);
                            acc[gg][t] = __builtin_amdgcn_mfma_f32_16x16x32_bf16(al[gg][kh], bh_[t][kh], acc[gg][t], 0, 0, 0);
                            acc[gg][t] = __builtin_amdgcn_mfma_f32_16x16x32_bf16(ah[gg][kh], bl_[t][kh], acc[gg][t], 0, 0, 0);
                        }
            }
        }

        // ---- epilogue: C -> T[d][m] (stride 67), per half ----
        __syncthreads();
        float* T = (float*)xsh;                    // 17168 B, fits xs[half]
#pragma unroll
        for (int gg = 0; gg < 2; ++gg)
#pragma unroll
            for (int t = 0; t < 2; ++t)
#pragma unroll
                for (int r = 0; r < 4; ++r) {
                    int d = nh * 32 + t * 16 + l15;
                    int m = mh * 32 + gg * 16 + l4 * 4 + r;
                    T[d * 67 + m] = acc[gg][t][r];
                }
        __syncthreads();
        if (tl < 128) {
            int m = tl & 63, sel = tl >> 6;
            float s = 0.f;
#pragma unroll
            for (int d = 0; d < 64; ++d) s += T[d * 67 + m] * sm.p1.asd[sel * 64 + d];
            (sel ? sdst : ssrc)[(size_t)head * BN + (size_t)b * Nn + i0loc + m] = s;
            // hbf pack -> lane-linear B-frag layout (region (b,jb,h) = 4KB)
            int dloc = tl >> 1, jh2 = tl & 1;
            const float* row = T + dloc * 67 + jh2 * 32;
            unsigned pk[16];
#pragma unroll
            for (int jj = 0; jj < 16; ++jj)
                pk[jj] = rne_bf16(row[jj * 2]) | (rne_bf16(row[jj * 2 + 1]) << 16);
            const int jb = (i0loc >> 5) + jh2;
            const int dt = dloc >> 4, fl = dloc & 15;
            unsigned short* rb = hbf +
                ((size_t)((b * 64 + jb) * 4 + head) * 2048 + dt * 512 + fl * 8);
            *(uint4*)(rb + 0 * 128) = make_uint4(pk[0],  pk[1],  pk[2],  pk[3]);
            *(uint4*)(rb + 1 * 128) = make_uint4(pk[4],  pk[5],  pk[6],  pk[7]);
            *(uint4*)(rb + 2 * 128) = make_uint4(pk[8],  pk[9],  pk[10], pk[11]);
            *(uint4*)(rb + 3 * 128) = make_uint4(pk[12], pk[13], pk[14], pk[15]);
        }
        __syncthreads();                           // all stores issued+drained
        if (tid == 0) {
            __threadfence();                       // L2 writeback (release)
            atomicAdd(&flags[b * 4 + head], 1u);   // target 16 per (b,head)
        }
    } else {
        // ---- compress: block covers 1024 bitmask words of ONE b ----
        const int c  = bid - 256;                  // 0..255
        const int cb = c >> 6;                     // b
        const int w0 = cb * 65536 + (c & 63) * 1024 + (tid >> 6) * 128;
        const int lane = tid & 63;
#pragma unroll 1
        for (int w = w0; w < w0 + 128; w += 4) {
            float v0 = adj[(size_t)((w + 0) >> 5) * 2048 + ((w + 0) & 31) * 64 + lane];
            float v1 = adj[(size_t)((w + 1) >> 5) * 2048 + ((w + 1) & 31) * 64 + lane];
            float v2 = adj[(size_t)((w + 2) >> 5) * 2048 + ((w + 2) & 31) * 64 + lane];
            float v3 = adj[(size_t)((w + 3) >> 5) * 2048 + ((w + 3) & 31) * 64 + lane];
            unsigned long long m0 = __ballot(v0 != 0.0f);
            unsigned long long m1 = __ballot(v1 != 0.0f);
            unsigned long long m2 = __ballot(v2 != 0.0f);
            unsigned long long m3 = __ballot(v3 != 0.0f);
            if (lane == 0) {
                bitadj[w + 0] = m0;
                bitadj[w + 1] = m1;
                bitadj[w + 2] = m2;
                bitadj[w + 3] = m3;
            }
        }
        __syncthreads();
        if (tid == 0) {
            __threadfence();
            atomicAdd(&flags[16 + cb], 1u);        // target 64 per b
        }
    }

    // =====================  PHASE 2: aggr (v10 body)  =====================
    const int xcd  = bid & 7;
    const int h    = xcd >> 1;
    const int bpar = xcd & 1;
    const int q    = bid >> 3;
    const int b2   = ((q & 1) << 1) | bpar;
    const int itile = q >> 1;
    const int i0 = itile * 64;

    // ---- gate: wait for this (b,h)'s producers ----
    if (tid == 0) {
        while (__hip_atomic_load(&flags[b2 * 4 + h], __ATOMIC_RELAXED, __HIP_MEMORY_SCOPE_AGENT) < 16u ||
               __hip_atomic_load(&flags[16 + b2],    __ATOMIC_RELAXED, __HIP_MEMORY_SCOPE_AGENT) < 64u)
            __builtin_amdgcn_s_sleep(2);
    }
    __syncthreads();
    __threadfence();                               // acquire: invalidate caches

    const int wv   = tid >> 6;
    const int isub = wv >> 1;
    const int jp   = wv & 1;
    const int ln = tid & 63, l15 = ln & 15, l4 = ln >> 4;

    const int ri   = (tid >> 7) & 3;
    const int soff = (tid & 127) * 16;

    {   // build exp-table for head h
        const int j4 = tid * 4;
        float4 sv = *(const float4*)(sdst + (size_t)h * BN + (size_t)b2 * Nn + j4);
        float4 o0 = make_float4(__expf(sv.x), __expf(0.2f * sv.x),
                                __expf(sv.y), __expf(0.2f * sv.y));
        float4 o1 = make_float4(__expf(sv.z), __expf(0.2f * sv.z),
                                __expf(sv.w), __expf(0.2f * sv.w));
        *(float4*)&sm.p2.dtab[j4 * 2]     = o0;
        *(float4*)&sm.p2.dtab[j4 * 2 + 4] = o1;
    }

    const int irow = i0 + isub * 16 + l15;
    const float ss = ssrc[(size_t)h * BN + (size_t)b2 * Nn + irow];
    const float c1 = __expf(ss), c2 = __expf(0.2f * ss);
    const unsigned char* ajr = (const unsigned char*)bitadj +
        ((size_t)b2 * Nn + irow) * 256;
    const unsigned short* sb2 = hbf +
        ((size_t)(b2 * 64 * 4) + h) * 2048 + soff;
    const float* dtb = sm.p2.dtab + l4 * 16;

    const v8s ones = {0x3F80, 0x3F80, 0x3F80, 0x3F80, 0x3F80, 0x3F80, 0x3F80, 0x3F80};

    v4f acc0 = (v4f){0.f, 0.f, 0.f, 0.f}, acc1 = acc0, acc2 = acc0, acc3 = acc0, zac = acc0;
    uint4 stg0, stg1;
    unsigned mA, mB;

#define GENFRAG(dst, M_, dd_) do {                                            \
        const float4 q0_ = *(const float4*)((dd_) + 0);                       \
        const float4 q1_ = *(const float4*)((dd_) + 4);                       \
        const float4 q2_ = *(const float4*)((dd_) + 8);                       \
        const float4 q3_ = *(const float4*)((dd_) + 12);                      \
        float w0_ = ((M_) & 1u)   ? fmaxf(c1 * q0_.x, c2 * q0_.y) : 0.f;      \
        float w1_ = ((M_) & 2u)   ? fmaxf(c1 * q0_.z, c2 * q0_.w) : 0.f;      \
        float w2_ = ((M_) & 4u)   ? fmaxf(c1 * q1_.x, c2 * q1_.y) : 0.f;      \
        float w3_ = ((M_) & 8u)   ? fmaxf(c1 * q1_.z, c2 * q1_.w) : 0.f;      \
        float w4_ = ((M_) & 16u)  ? fmaxf(c1 * q2_.x, c2 * q2_.y) : 0.f;      \
        float w5_ = ((M_) & 32u)  ? fmaxf(c1 * q2_.z, c2 * q2_.w) : 0.f;      \
        float w6_ = ((M_) & 64u)  ? fmaxf(c1 * q3_.x, c2 * q3_.y) : 0.f;      \
        float w7_ = ((M_) & 128u) ? fmaxf(c1 * q3_.z, c2 * q3_.w) : 0.f;      \
        union { v8s v; unsigned u[4]; } P_;                                   \
        asm("v_cvt_pk_bf16_f32 %0, %1, %2" : "=v"(P_.u[0]) : "v"(w0_), "v"(w1_)); \
        asm("v_cvt_pk_bf16_f32 %0, %1, %2" : "=v"(P_.u[1]) : "v"(w2_), "v"(w3_)); \
        asm("v_cvt_pk_bf16_f32 %0, %1, %2" : "=v"(P_.u[2]) : "v"(w4_), "v"(w5_)); \
        asm("v_cvt_pk_bf16_f32 %0, %1, %2" : "=v"(P_.u[3]) : "v"(w6_), "v"(w7_)); \
        dst = P_.v;                                                           \
    } while (0)

#define COMPUTE(JC_, M_, btp) do {                                            \
        const unsigned short* bp_ = (btp);                                    \
        v8s bf0_ = *(const v8s*)(bp_ + 0 * 512 + ln * 8);                     \
        v8s bf1_ = *(const v8s*)(bp_ + 1 * 512 + ln * 8);                     \
        v8s bf2_ = *(const v8s*)(bp_ + 2 * 512 + ln * 8);                     \
        v8s bf3_ = *(const v8s*)(bp_ + 3 * 512 + ln * 8);                     \
        const float* dd_ = dtb + (JC_) * 64;                                  \
        v8s afr_;                                                             \
        GENFRAG(afr_, M_, dd_);                                               \
        acc0 = __builtin_amdgcn_mfma_f32_16x16x32_bf16(afr_, bf0_, acc0, 0, 0, 0); \
        acc1 = __builtin_amdgcn_mfma_f32_16x16x32_bf16(afr_, bf1_, acc1, 0, 0, 0); \
        acc2 = __builtin_amdgcn_mfma_f32_16x16x32_bf16(afr_, bf2_, acc2, 0, 0, 0); \
        acc3 = __builtin_amdgcn_mfma_f32_16x16x32_bf16(afr_, bf3_, acc3, 0, 0, 0); \
        zac  = __builtin_amdgcn_mfma_f32_16x16x32_bf16(afr_, ones, zac,  0, 0, 0); \
    } while (0)

    // ---- prologue: stage super-round 0 (regions jc=0..3) into buf0 ----
    stg0 = *(const uint4*)(sb2 + (size_t)ri * 8192);
    stg1 = *(const uint4*)(sb2 + (size_t)ri * 8192 + 8);
    mA = ajr[jp * 4 + l4];
    mB = ajr[(2 + jp) * 4 + l4];
    *(uint4*)&sm.p2.Btile[0][ri][soff]     = stg0;
    *(uint4*)&sm.p2.Btile[0][ri][soff + 8] = stg1;
    __syncthreads();

#pragma unroll 1
    for (int sr = 0; sr < 16; ++sr) {
        const int buf = sr & 1;
        const int jq = ((sr + 1) & 15) * 4;
        stg0 = *(const uint4*)(sb2 + (size_t)(jq + ri) * 8192);
        stg1 = *(const uint4*)(sb2 + (size_t)(jq + ri) * 8192 + 8);
        const unsigned mA2 = ajr[(jq + jp) * 4 + l4];
        const unsigned mB2 = ajr[(jq + 2 + jp) * 4 + l4];
        __builtin_amdgcn_sched_barrier(0);
        COMPUTE(4 * sr + jp,     mA, sm.p2.Btile[buf][jp]);
        COMPUTE(4 * sr + 2 + jp, mB, sm.p2.Btile[buf][2 + jp]);
        *(uint4*)&sm.p2.Btile[buf ^ 1][ri][soff]     = stg0;
        *(uint4*)&sm.p2.Btile[buf ^ 1][ri][soff + 8] = stg1;
        mA = mA2; mB = mB2;
        __syncthreads();
    }

#undef GENFRAG
#undef COMPUTE

    // ---- jp-combine via LDS; jp=0 waves normalize + exclusive store ----
    if (jp) {
        float* rp = &sm.p2.red[isub][ln][0];
        *(v4f*)(rp + 0)  = acc0;
        *(v4f*)(rp + 4)  = acc1;
        *(v4f*)(rp + 8)  = acc2;
        *(v4f*)(rp + 12) = acc3;
        *(v4f*)(rp + 16) = zac;
    }
    __syncthreads();
    if (!jp) {
        const float* rp = &sm.p2.red[isub][ln][0];
        acc0 += *(const v4f*)(rp + 0);
        acc1 += *(const v4f*)(rp + 4);
        acc2 += *(const v4f*)(rp + 8);
        acc3 += *(const v4f*)(rp + 12);
        zac  += *(const v4f*)(rp + 16);
        float* op = out + ((size_t)b2 * Nn + i0 + isub * 16 + l4 * 4) * Dd + h * HDd + l15;
#pragma unroll
        for (int r = 0; r < 4; ++r) {
            float zi = 1.f / zac[r];
            op[(size_t)r * Dd + 0]  = acc0[r] * zi;
            op[(size_t)r * Dd + 16] = acc1[r] * zi;
            op[(size_t)r * Dd + 32] = acc2[r] * zi;
            op[(size_t)r * Dd + 48] = acc3[r] * zi;
        }
    }
}

extern "C" void kernel_launch(void* const* d_in, const int* in_sizes, int n_in,
                              void* d_out, int out_size, void* d_ws, size_t ws_size,
                              hipStream_t stream) {
    const float* x     = (const float*)d_in[0];
    const float* adj   = (const float*)d_in[1];
    const float* W     = (const float*)d_in[2];
    const float* a_src = (const float*)d_in[3];
    const float* a_dst = (const float*)d_in[4];
    float* out = (float*)d_out;

    // ws: hbf 4MB | ssrc 128KB | sdst 128KB | bitadj 2MB | flags 128B
    unsigned short* hbf = (unsigned short*)d_ws;
    float* ssrc = (float*)(hbf + (size_t)Bb * Nn * Dd);
    float* sdst = ssrc + (size_t)Hh * BN;
    unsigned long long* bitadj = (unsigned long long*)(sdst + (size_t)Hh * BN);
    unsigned* flags = (unsigned*)(bitadj + 262144);

    hipMemsetAsync(flags, 0, 32 * sizeof(unsigned), stream);
    k_fused<<<dim3(512), dim3(512), 0, stream>>>(x, W, a_src, a_dst, adj,
                                                 hbf, ssrc, sdst, bitadj, flags, out);
}

// Round 11
// 138.681 us; speedup vs baseline: 1.9406x; 1.9406x over previous
//
#include <hip/hip_runtime.h>
#include <math.h>

#define Bb   4
#define Nn   2048
#define Dd   256
#define Hh   4
#define HDd  64
#define BN   (Bb * Nn)

typedef float v4f __attribute__((ext_vector_type(4)));
typedef short v8s __attribute__((ext_vector_type(8)));

__device__ __forceinline__ unsigned rne_bf16(float f) {
    unsigned u = __float_as_uint(f);
    u += 0x7fffu + ((u >> 16) & 1u);
    return u >> 16;
}

// ---------------------------------------------------------------------------
// Kernel 1: role-split grid of 1024 blocks.
//   bid even -> gemm ; bid odd -> adj->bitmask compress.
// hbf layout: lane-linear B-frag regions; region (b,jb,h)=4KB at shorts
// ((b*64+jb)*4+h)*2048; d-tile dt at dt*512; lane ln at ln*8.
// ---------------------------------------------------------------------------
__global__ __launch_bounds__(256, 2) void k_gemm(const float* __restrict__ x,
                                                 const float* __restrict__ W,
                                                 const float* __restrict__ a_src,
                                                 const float* __restrict__ a_dst,
                                                 const float* __restrict__ adj,
                                                 unsigned short* __restrict__ hbf,
                                                 float* __restrict__ ssrc,
                                                 float* __restrict__ sdst,
                                                 unsigned long long* __restrict__ bitadj) {
    __shared__ __align__(16) unsigned short xs[2][64 * 72];  // hi, lo  (T reuses xs)
    __shared__ __align__(16) unsigned short wsm[2][64 * 72];
    __shared__ float asd[128];

    const int bid0 = (int)blockIdx.x;
    if (bid0 & 1) {
        const int gw = (bid0 >> 1) * 4 + ((int)threadIdx.x >> 6);
        const int lane = (int)threadIdx.x & 63;
#pragma unroll 1
        for (int w = gw * 4; w < 262144; w += 2048 * 4) {
            float v0 = adj[(size_t)((w + 0) >> 5) * 2048 + ((w + 0) & 31) * 64 + lane];
            float v1 = adj[(size_t)((w + 1) >> 5) * 2048 + ((w + 1) & 31) * 64 + lane];
            float v2 = adj[(size_t)((w + 2) >> 5) * 2048 + ((w + 2) & 31) * 64 + lane];
            float v3 = adj[(size_t)((w + 3) >> 5) * 2048 + ((w + 3) & 31) * 64 + lane];
            unsigned long long m0 = __ballot(v0 != 0.0f);
            unsigned long long m1 = __ballot(v1 != 0.0f);
            unsigned long long m2 = __ballot(v2 != 0.0f);
            unsigned long long m3 = __ballot(v3 != 0.0f);
            if (lane == 0) {
                bitadj[w + 0] = m0;
                bitadj[w + 1] = m1;
                bitadj[w + 2] = m2;
                bitadj[w + 3] = m3;
            }
        }
        return;
    }

    const int g = bid0 >> 1;                       // [0,512)
    const int head = (g >> 2) & 3;
    const int mtile = (g & 3) + 4 * (g >> 4);
    const int tid = threadIdx.x;
    const int m0 = mtile * 64;
    const int n0 = head * 64;
    const int b = m0 >> 11;
    const int i0loc = m0 & 2047;

    if (tid < 128) {
        int sel = tid >> 6, d = tid & 63;
        asd[tid] = sel ? a_dst[n0 + d] : a_src[n0 + d];
    }

    const int wv = tid >> 6, ln = tid & 63, l15 = ln & 15, l4 = ln >> 4;
    const int mh = wv >> 1, nh = wv & 1;
    const int srow = tid >> 2, kq = (tid & 3) * 16;

    v4f acc[2][2];
#pragma unroll
    for (int gg = 0; gg < 2; ++gg)
#pragma unroll
        for (int t = 0; t < 2; ++t) acc[gg][t] = (v4f){0.f, 0.f, 0.f, 0.f};

    for (int st = 0; st < 4; ++st) {
        const int k0 = st * 64;
        __syncthreads();
        {
            float xf[16], wf[16];
            const float* xp = x + (size_t)(m0 + srow) * Dd + k0 + kq;
            const float* wp = W + (size_t)(n0 + srow) * Dd + k0 + kq;
#pragma unroll
            for (int q = 0; q < 4; ++q) {
                *(float4*)&xf[q * 4] = *(const float4*)(xp + q * 4);
                *(float4*)&wf[q * 4] = *(const float4*)(wp + q * 4);
            }
            unsigned xh[8], xl[8], wh[8], wl[8];
#pragma unroll
            for (int j = 0; j < 8; ++j) {
                unsigned h0 = rne_bf16(xf[2 * j]), h1 = rne_bf16(xf[2 * j + 1]);
                float l0 = xf[2 * j] - __uint_as_float(h0 << 16);
                float l1 = xf[2 * j + 1] - __uint_as_float(h1 << 16);
                xh[j] = h0 | (h1 << 16);
                xl[j] = rne_bf16(l0) | (rne_bf16(l1) << 16);
                unsigned g0 = rne_bf16(wf[2 * j]), g1 = rne_bf16(wf[2 * j + 1]);
                float m0f = wf[2 * j] - __uint_as_float(g0 << 16);
                float m1f = wf[2 * j + 1] - __uint_as_float(g1 << 16);
                wh[j] = g0 | (g1 << 16);
                wl[j] = rne_bf16(m0f) | (rne_bf16(m1f) << 16);
            }
            *(uint4*)(xs[0] + srow * 72 + kq)     = make_uint4(xh[0], xh[1], xh[2], xh[3]);
            *(uint4*)(xs[0] + srow * 72 + kq + 8) = make_uint4(xh[4], xh[5], xh[6], xh[7]);
            *(uint4*)(xs[1] + srow * 72 + kq)     = make_uint4(xl[0], xl[1], xl[2], xl[3]);
            *(uint4*)(xs[1] + srow * 72 + kq + 8) = make_uint4(xl[4], xl[5], xl[6], xl[7]);
            *(uint4*)(wsm[0] + srow * 72 + kq)     = make_uint4(wh[0], wh[1], wh[2], wh[3]);
            *(uint4*)(wsm[0] + srow * 72 + kq + 8) = make_uint4(wh[4], wh[5], wh[6], wh[7]);
            *(uint4*)(wsm[1] + srow * 72 + kq)     = make_uint4(wl[0], wl[1], wl[2], wl[3]);
            *(uint4*)(wsm[1] + srow * 72 + kq + 8) = make_uint4(wl[4], wl[5], wl[6], wl[7]);
        }
        __syncthreads();
        {
            v8s ah[2][2], al[2][2], bh_[2][2], bl_[2][2];
#pragma unroll
            for (int gg = 0; gg < 2; ++gg)
#pragma unroll
                for (int kh = 0; kh < 2; ++kh) {
                    int ro = (mh * 32 + gg * 16 + l15) * 72 + kh * 32 + l4 * 8;
                    ah[gg][kh] = *(const v8s*)(xs[0] + ro);
                    al[gg][kh] = *(const v8s*)(xs[1] + ro);
                }
#pragma unroll
            for (int t = 0; t < 2; ++t)
#pragma unroll
                for (int kh = 0; kh < 2; ++kh) {
                    int ro = (nh * 32 + t * 16 + l15) * 72 + kh * 32 + l4 * 8;
                    bh_[t][kh] = *(const v8s*)(wsm[0] + ro);
                    bl_[t][kh] = *(const v8s*)(wsm[1] + ro);
                }
#pragma unroll
            for (int gg = 0; gg < 2; ++gg)
#pragma unroll
                for (int t = 0; t < 2; ++t)
#pragma unroll
                    for (int kh = 0; kh < 2; ++kh) {
                        acc[gg][t] = __builtin_amdgcn_mfma_f32_16x16x32_bf16(ah[gg][kh], bh_[t][kh], acc[gg][t], 0, 0, 0);
                        acc[gg][t] = __builtin_amdgcn_mfma_f32_16x16x32_bf16(al[gg][kh], bh_[t][kh], acc[gg][t], 0, 0, 0);
                        acc[gg][t] = __builtin_amdgcn_mfma_f32_16x16x32_bf16(ah[gg][kh], bl_[t][kh], acc[gg][t], 0, 0, 0);
                    }
        }
    }

    __syncthreads();
    float* T = (float*)&xs[0][0];   // 64*67*4 = 17168 B
#pragma unroll
    for (int gg = 0; gg < 2; ++gg)
#pragma unroll
        for (int t = 0; t < 2; ++t)
#pragma unroll
            for (int r = 0; r < 4; ++r) {
                int d = nh * 32 + t * 16 + l15;
                int m = mh * 32 + gg * 16 + l4 * 4 + r;
                T[d * 67 + m] = acc[gg][t][r];
            }
    __syncthreads();
    if (tid < 128) {
        int m = tid & 63, sel = tid >> 6;
        float s = 0.f;
#pragma unroll
        for (int d = 0; d < 64; ++d) s += T[d * 67 + m] * asd[sel * 64 + d];
        (sel ? sdst : ssrc)[(size_t)head * BN + (size_t)b * Nn + i0loc + m] = s;
        // hbf pack -> lane-linear B-frag layout
        int dloc = tid >> 1, jh2 = tid & 1;
        const float* row = T + dloc * 67 + jh2 * 32;
        unsigned pk[16];
#pragma unroll
        for (int jj = 0; jj < 16; ++jj)
            pk[jj] = rne_bf16(row[jj * 2]) | (rne_bf16(row[jj * 2 + 1]) << 16);
        const int jb = (i0loc >> 5) + jh2;
        const int dt = dloc >> 4, fl = dloc & 15;
        unsigned short* rb = hbf +
            ((size_t)((b * 64 + jb) * 4 + head) * 2048 + dt * 512 + fl * 8);
        *(uint4*)(rb + 0 * 128) = make_uint4(pk[0],  pk[1],  pk[2],  pk[3]);
        *(uint4*)(rb + 1 * 128) = make_uint4(pk[4],  pk[5],  pk[6],  pk[7]);
        *(uint4*)(rb + 2 * 128) = make_uint4(pk[8],  pk[9],  pk[10], pk[11]);
        *(uint4*)(rb + 3 * 128) = make_uint4(pk[12], pk[13], pk[14], pk[15]);
    }
}

// ---------------------------------------------------------------------------
// Kernel 2 (v10, session best): LDS-staged B pipeline with SUPER-ROUND
// staging.  Block = (b, ONE head, 64 i-rows); grid 512, XCD-bijective.
// 8 waves = (isub 4) x (jp 2); per round: 1 generated A-frag (exp-hoisted
// gen via dtab), 4 ds_read_b128 B-frags, 4 acc MFMA + 1 z.  4 regions
// (16 KB) staged per sync; 2 rounds computed per barrier; masks prefetched
// a super-round ahead.  Register economy: stg = 8 VGPR (prefetch lives in
// LDS, not the register file -- the session's key lesson).
// ---------------------------------------------------------------------------
__global__ __launch_bounds__(512, 4) void k_aggr(const unsigned short* __restrict__ hbf,
                                                 const unsigned long long* __restrict__ bitadj,
                                                 const float* __restrict__ ssrc,
                                                 const float* __restrict__ sdst,
                                                 float* __restrict__ out) {
    __shared__ __align__(16) unsigned short Btile[2][4][2048];  // 32 KB dbuf x 4 regions
    __shared__ __align__(16) float dtab[2048 * 2];              // 16 KB exp-table
    __shared__ __align__(16) float red[4][64][20];              // 20 KB jp-combine

    const int tid = threadIdx.x;
    const int bid = (int)blockIdx.x;
    const int xcd  = bid & 7;
    const int h    = xcd >> 1;             // one head per XCD pair
    const int bpar = xcd & 1;
    const int q    = bid >> 3;             // 0..63
    const int b    = ((q & 1) << 1) | bpar;
    const int itile = q >> 1;              // 0..31 -> 64 i-rows
    const int i0 = itile * 64;

    const int wv   = tid >> 6;
    const int isub = wv >> 1;              // 0..3 (16 i-rows each)
    const int jp   = wv & 1;               // j-chunk parity
    const int ln = tid & 63, l15 = ln & 15, l4 = ln >> 4;

    // staging role: thread stages 32B of one region per super-round
    const int ri   = (tid >> 7) & 3;       // region index 0..3
    const int soff = (tid & 127) * 16;     // shorts within region

    // ---- build exp-table for head h: j -> (exp(sd), exp(.2 sd)) ----
    {
        const int j4 = tid * 4;
        float4 sv = *(const float4*)(sdst + (size_t)h * BN + (size_t)b * Nn + j4);
        float4 o0 = make_float4(__expf(sv.x), __expf(0.2f * sv.x),
                                __expf(sv.y), __expf(0.2f * sv.y));
        float4 o1 = make_float4(__expf(sv.z), __expf(0.2f * sv.z),
                                __expf(sv.w), __expf(0.2f * sv.w));
        *(float4*)&dtab[j4 * 2]     = o0;
        *(float4*)&dtab[j4 * 2 + 4] = o1;
    }

    const int irow = i0 + isub * 16 + l15;         // lane's A-row (m = l15)
    const float ss = ssrc[(size_t)h * BN + (size_t)b * Nn + irow];
    const float c1 = __expf(ss), c2 = __expf(0.2f * ss);
    const unsigned char* ajr = (const unsigned char*)bitadj +
        ((size_t)b * Nn + irow) * 256;
    // staging source: region jc at base + jc*8192 shorts
    const unsigned short* sb2 = hbf +
        ((size_t)(b * 64 * 4) + h) * 2048 + soff;
    const float* dtb = dtab + l4 * 16;

    const v8s ones = {0x3F80, 0x3F80, 0x3F80, 0x3F80, 0x3F80, 0x3F80, 0x3F80, 0x3F80};

    v4f acc0 = (v4f){0.f, 0.f, 0.f, 0.f}, acc1 = acc0, acc2 = acc0, acc3 = acc0, zac = acc0;
    uint4 stg0, stg1;
    unsigned mA, mB;

    // w = bit ? max(c1*e1, c2*e2) : 0  ==  bit ? exp(max(s,0.2s)) : 0
#define GENFRAG(dst, M_, dd_) do {                                            \
        const float4 q0_ = *(const float4*)((dd_) + 0);                       \
        const float4 q1_ = *(const float4*)((dd_) + 4);                       \
        const float4 q2_ = *(const float4*)((dd_) + 8);                       \
        const float4 q3_ = *(const float4*)((dd_) + 12);                      \
        float w0_ = ((M_) & 1u)   ? fmaxf(c1 * q0_.x, c2 * q0_.y) : 0.f;      \
        float w1_ = ((M_) & 2u)   ? fmaxf(c1 * q0_.z, c2 * q0_.w) : 0.f;      \
        float w2_ = ((M_) & 4u)   ? fmaxf(c1 * q1_.x, c2 * q1_.y) : 0.f;      \
        float w3_ = ((M_) & 8u)   ? fmaxf(c1 * q1_.z, c2 * q1_.w) : 0.f;      \
        float w4_ = ((M_) & 16u)  ? fmaxf(c1 * q2_.x, c2 * q2_.y) : 0.f;      \
        float w5_ = ((M_) & 32u)  ? fmaxf(c1 * q2_.z, c2 * q2_.w) : 0.f;      \
        float w6_ = ((M_) & 64u)  ? fmaxf(c1 * q3_.x, c2 * q3_.y) : 0.f;      \
        float w7_ = ((M_) & 128u) ? fmaxf(c1 * q3_.z, c2 * q3_.w) : 0.f;      \
        union { v8s v; unsigned u[4]; } P_;                                   \
        asm("v_cvt_pk_bf16_f32 %0, %1, %2" : "=v"(P_.u[0]) : "v"(w0_), "v"(w1_)); \
        asm("v_cvt_pk_bf16_f32 %0, %1, %2" : "=v"(P_.u[1]) : "v"(w2_), "v"(w3_)); \
        asm("v_cvt_pk_bf16_f32 %0, %1, %2" : "=v"(P_.u[2]) : "v"(w4_), "v"(w5_)); \
        asm("v_cvt_pk_bf16_f32 %0, %1, %2" : "=v"(P_.u[3]) : "v"(w6_), "v"(w7_)); \
        dst = P_.v;                                                           \
    } while (0)

#define COMPUTE(JC_, M_, btp) do {                                            \
        const unsigned short* bp_ = (btp);                                    \
        v8s bf0_ = *(const v8s*)(bp_ + 0 * 512 + ln * 8);                     \
        v8s bf1_ = *(const v8s*)(bp_ + 1 * 512 + ln * 8);                     \
        v8s bf2_ = *(const v8s*)(bp_ + 2 * 512 + ln * 8);                     \
        v8s bf3_ = *(const v8s*)(bp_ + 3 * 512 + ln * 8);                     \
        const float* dd_ = dtb + (JC_) * 64;                                  \
        v8s afr_;                                                             \
        GENFRAG(afr_, M_, dd_);                                               \
        acc0 = __builtin_amdgcn_mfma_f32_16x16x32_bf16(afr_, bf0_, acc0, 0, 0, 0); \
        acc1 = __builtin_amdgcn_mfma_f32_16x16x32_bf16(afr_, bf1_, acc1, 0, 0, 0); \
        acc2 = __builtin_amdgcn_mfma_f32_16x16x32_bf16(afr_, bf2_, acc2, 0, 0, 0); \
        acc3 = __builtin_amdgcn_mfma_f32_16x16x32_bf16(afr_, bf3_, acc3, 0, 0, 0); \
        zac  = __builtin_amdgcn_mfma_f32_16x16x32_bf16(afr_, ones, zac,  0, 0, 0); \
    } while (0)

    // ---- prologue: stage super-round 0 (regions jc=0..3) into buf0 ----
    stg0 = *(const uint4*)(sb2 + (size_t)ri * 8192);
    stg1 = *(const uint4*)(sb2 + (size_t)ri * 8192 + 8);
    mA = ajr[jp * 4 + l4];
    mB = ajr[(2 + jp) * 4 + l4];
    *(uint4*)&Btile[0][ri][soff]     = stg0;   // compiler waits vmcnt
    *(uint4*)&Btile[0][ri][soff + 8] = stg1;
    __syncthreads();                           // buf0 + dtab ready

#pragma unroll 1
    for (int sr = 0; sr < 16; ++sr) {
        const int buf = sr & 1;
        // ---- issue next super-round's loads (covered by 2 compute rounds)
        const int jq = ((sr + 1) & 15) * 4;
        stg0 = *(const uint4*)(sb2 + (size_t)(jq + ri) * 8192);
        stg1 = *(const uint4*)(sb2 + (size_t)(jq + ri) * 8192 + 8);
        const unsigned mA2 = ajr[(jq + jp) * 4 + l4];
        const unsigned mB2 = ajr[(jq + 2 + jp) * 4 + l4];
        __builtin_amdgcn_sched_barrier(0);     // pin loads above compute
        // ---- compute 2 rounds from buf ----
        COMPUTE(4 * sr + jp,     mA, Btile[buf][jp]);
        COMPUTE(4 * sr + 2 + jp, mB, Btile[buf][2 + jp]);
        // ---- land staged data (vmcnt wait here, after compute) ----
        *(uint4*)&Btile[buf ^ 1][ri][soff]     = stg0;
        *(uint4*)&Btile[buf ^ 1][ri][soff + 8] = stg1;
        mA = mA2; mB = mB2;
        __syncthreads();
    }

#undef GENFRAG
#undef COMPUTE

    // ---- jp-combine via LDS; jp=0 waves normalize + exclusive store ----
    if (jp) {
        float* rp = &red[isub][ln][0];
        *(v4f*)(rp + 0)  = acc0;
        *(v4f*)(rp + 4)  = acc1;
        *(v4f*)(rp + 8)  = acc2;
        *(v4f*)(rp + 12) = acc3;
        *(v4f*)(rp + 16) = zac;
    }
    __syncthreads();
    if (!jp) {
        const float* rp = &red[isub][ln][0];
        acc0 += *(const v4f*)(rp + 0);
        acc1 += *(const v4f*)(rp + 4);
        acc2 += *(const v4f*)(rp + 8);
        acc3 += *(const v4f*)(rp + 12);
        zac  += *(const v4f*)(rp + 16);
        float* op = out + ((size_t)b * Nn + i0 + isub * 16 + l4 * 4) * Dd + h * HDd + l15;
#pragma unroll
        for (int r = 0; r < 4; ++r) {
            float zi = 1.f / zac[r];
            op[(size_t)r * Dd + 0]  = acc0[r] * zi;
            op[(size_t)r * Dd + 16] = acc1[r] * zi;
            op[(size_t)r * Dd + 32] = acc2[r] * zi;
            op[(size_t)r * Dd + 48] = acc3[r] * zi;
        }
    }
}

extern "C" void kernel_launch(void* const* d_in, const int* in_sizes, int n_in,
                              void* d_out, int out_size, void* d_ws, size_t ws_size,
                              hipStream_t stream) {
    const float* x     = (const float*)d_in[0];
    const float* adj   = (const float*)d_in[1];
    const float* W     = (const float*)d_in[2];
    const float* a_src = (const float*)d_in[3];
    const float* a_dst = (const float*)d_in[4];
    float* out = (float*)d_out;

    // ws: hbf 4MB | ssrc [h][bn] 128KB | sdst [h][bn] 128KB | bitadj 2MB
    unsigned short* hbf = (unsigned short*)d_ws;
    float* ssrc = (float*)(hbf + (size_t)Bb * Nn * Dd);
    float* sdst = ssrc + (size_t)Hh * BN;
    unsigned long long* bitadj = (unsigned long long*)(sdst + (size_t)Hh * BN);

    k_gemm<<<dim3(1024), dim3(256), 0, stream>>>(x, W, a_src, a_dst, adj,
                                                 hbf, ssrc, sdst, bitadj);
    k_aggr<<<dim3(512), dim3(512), 0, stream>>>(hbf, bitadj, ssrc, sdst, out);
}